// Round 6
// baseline (593.640 us; speedup 1.0000x reference)
//
#include <hip/hip_runtime.h>
#include <hip/hip_bf16.h>
#include <cstdint>
#include <type_traits>

typedef unsigned short u16;
typedef __attribute__((ext_vector_type(8))) short short8;
typedef __attribute__((ext_vector_type(4))) float floatx4;

__device__ __forceinline__ u16 f2bf(float f) {
  union { float f; uint32_t u; } v; v.f = f;
  uint32_t u = v.u;
  return (u16)((u + 0x7FFFu + ((u >> 16) & 1u)) >> 16);
}
__device__ __forceinline__ float bf2f(u16 h) {
  union { uint32_t u; float f; } v; v.u = ((uint32_t)h) << 16;
  return v.f;
}

// global -> LDS direct, 16B per lane. LDS dest is wave-uniform base + lane*16
// (m104); global src is per-lane.
typedef const __attribute__((address_space(1))) char GChar;
typedef __attribute__((address_space(3))) char LChar;
__device__ __forceinline__ void gload_lds16(const void* g, void* l) {
  __builtin_amdgcn_global_load_lds((GChar*)g, (LChar*)l, 16, 0, 0);
}

// T1: bijective XCD swizzle (nwg % 8 == 0 for all our grids)
__device__ __forceinline__ int xcd_swz(int id, int nwg) {
  int cpx = nwg >> 3;
  return (id & 7) * cpx + (id >> 3);
}

// ---------------- elementwise: fp32 -> bf16 cast ----------------
__global__ void cast_f32_bf16(const float* __restrict__ src, u16* __restrict__ dst, int n) {
  int i = (blockIdx.x * blockDim.x + threadIdx.x) * 4;
  int stride = gridDim.x * blockDim.x * 4;
  for (; i < n; i += stride) {
    float4 v = *reinterpret_cast<const float4*>(src + i);
    ushort4 o;
    o.x = f2bf(v.x); o.y = f2bf(v.y); o.z = f2bf(v.z); o.w = f2bf(v.w);
    *reinterpret_cast<ushort4*>(dst + i) = o;
  }
}

// ---------------- RoPE tables (matches reference: theta=10000^(-2(i-1)/D)) --
__global__ void rope_tables(float* __restrict__ cosT, float* __restrict__ sinT) {
  int idx = blockIdx.x * blockDim.x + threadIdx.x;   // m*512 + i
  int m = idx >> 9;
  int i = idx & 511;
  double ex = -2.0 * ((double)i - 1.0) / 1024.0;
  double theta = exp(ex * log(10000.0));
  double ang = (double)m * theta;
  cosT[idx] = (float)cos(ang);
  sinT[idx] = (float)sin(ang);
}

// ---------------- GEMM-BT: C[i][j] = scale * sum_k A[i][k]*W[j][k] ---------
// A,W bf16 row-major; C fp32 or bf16. 128x128 tile, BK=64, 4 waves (2x2 of 64x64),
// mfma_f32_16x16x32_bf16, global_load_lds width-16 staging.
// XCD swizzle: tn-fast within chunk (A-panel shared by consecutive blocks;
// each XCD owns a contiguous tm band). ropeCols > 0: fused RoPE on cols < ropeCols.
template <typename CT>
__global__ __launch_bounds__(256) void gemm_bt(
    const u16* __restrict__ A, const u16* __restrict__ Bw, CT* __restrict__ C,
    int K, long lda, long ldb, long ldc,
    long strideA, long strideB, long strideC, float scale,
    const float* __restrict__ cosT, const float* __restrict__ sinT, int ropeCols)
{
  __shared__ u16 As[128 * 64];
  __shared__ u16 Bs[128 * 64];

  const int bz = blockIdx.z;
  A  += (long)bz * strideA;
  Bw += (long)bz * strideB;
  C  += (long)bz * strideC;

  // XCD chunking over tm bands, tn-fast inside (preserves A-panel sharing)
  const int nwg = gridDim.x * gridDim.y;
  const int swz = xcd_swz(blockIdx.y * gridDim.x + blockIdx.x, nwg);
  const int tn = swz % gridDim.x, tm = swz / gridDim.x;

  const int t = threadIdx.x;
  const int lane = t & 63, wave = t >> 6;
  const int wm = (wave >> 1) * 64, wn = (wave & 1) * 64;

  // staging: thread t covers 16B = row t/8 + 32*p, col (t%8)*8  (p = 0..3)
  const int srow = t >> 3;
  const int scol = (t & 7) * 8;
  const u16* Ag = A + (long)(tm * 128 + srow) * lda + scol;
  const u16* Bg = Bw + (long)(tn * 128 + srow) * ldb + scol;
  u16* AsW = As + wave * 512;   // wave-uniform base; lane lands at +lane*8
  u16* BsW = Bs + wave * 512;

  floatx4 acc[4][4];
#pragma unroll
  for (int m = 0; m < 4; ++m)
#pragma unroll
    for (int n = 0; n < 4; ++n) acc[m][n] = (floatx4){0.f, 0.f, 0.f, 0.f};

  const int arow0 = (lane & 15) * 64 + ((lane >> 4) * 8);  // row*(BK=64)+kgroup
  const int nk = K >> 6;
  for (int kt = 0; kt < nk; ++kt) {
    __syncthreads();  // previous tile fully consumed
    const u16* ag = Ag + kt * 64;
    const u16* bg = Bg + kt * 64;
#pragma unroll
    for (int p = 0; p < 4; ++p) {
      gload_lds16(ag + (long)(32 * p) * lda, AsW + p * 2048);
      gload_lds16(bg + (long)(32 * p) * ldb, BsW + p * 2048);
    }
    __syncthreads();  // drains vmcnt -> tile ready

#pragma unroll
    for (int kk = 0; kk < 2; ++kk) {
      short8 af[4], bf[4];
#pragma unroll
      for (int m = 0; m < 4; ++m)
        af[m] = *reinterpret_cast<const short8*>(&As[(wm + m * 16) * 64 + arow0 + kk * 32]);
#pragma unroll
      for (int n = 0; n < 4; ++n)
        bf[n] = *reinterpret_cast<const short8*>(&Bs[(wn + n * 16) * 64 + arow0 + kk * 32]);
#pragma unroll
      for (int m = 0; m < 4; ++m)
#pragma unroll
        for (int n = 0; n < 4; ++n)
          acc[m][n] = __builtin_amdgcn_mfma_f32_16x16x32_bf16(af[m], bf[n], acc[m][n], 0, 0, 0);
    }
  }

  // epilogue: C/D layout col=lane&15, row=(lane>>4)*4+r (m89/m91 verified)
  const long crow = (long)tm * 128 + wm + ((lane >> 4) << 2);
  const long ccol = (long)tn * 128 + wn + (lane & 15);
  const bool doRope = (ropeCols > 0) && (tn * 128 < ropeCols);  // block-uniform
  const int par = lane & 1;
#pragma unroll
  for (int m = 0; m < 4; ++m)
#pragma unroll
    for (int n = 0; n < 4; ++n)
#pragma unroll
      for (int r = 0; r < 4; ++r) {
        long row = crow + m * 16 + r;
        long col = ccol + n * 16;
        float val = acc[m][n][r] * scale;
        if (doRope) {
          // pair (even col = te, odd col = to) lives on lanes (l, l^1)
          float other = __shfl_xor(val, 1, 64);
          int i  = ((int)(col & 1023)) >> 1;   // Q (col<1024) and K (col-1024)
          int mm = (int)(row & 2047);
          float c = cosT[mm * 512 + i];
          float s = sinT[mm * 512 + i];
          // even lane: re = te*c + to*s ; odd lane: ro = -te*s + to*c
          val = par ? (val * c - other * s) : (val * c + other * s);
        }
        if constexpr (std::is_same<CT, u16>::value)
          C[row * ldc + col] = f2bf(val);
        else
          C[row * ldc + col] = val;
      }
}

// ---------------- V transpose: vt[b][d][m] = V[b][m][d] ---------------------
__global__ void transpose_v(const u16* __restrict__ qkv, u16* __restrict__ vt) {
  __shared__ u16 tile[32][33];
  int b = blockIdx.z;
  int m0 = blockIdx.y * 32, d0 = blockIdx.x * 32;
  int tx = threadIdx.x & 31, ty = threadIdx.x >> 5;  // 32x8
#pragma unroll
  for (int r = ty; r < 32; r += 8)
    tile[r][tx] = qkv[(long)(b * 2048 + m0 + r) * 3072 + 2048 + d0 + tx];
  __syncthreads();
#pragma unroll
  for (int r = ty; r < 32; r += 8)
    vt[(long)b * 1024 * 2048 + (long)(d0 + r) * 2048 + m0 + tx] = tile[tx][r];
}

// ------------- row softmax on bf16 scores, P bf16 written in place ----------
__global__ __launch_bounds__(256) void softmax_rows_bf16(u16* __restrict__ S) {
  const long base = (long)blockIdx.x * 2048;
  const int t = threadIdx.x, lane = t & 63, wave = t >> 6;
  short8 in8 = *reinterpret_cast<const short8*>(&S[base + t * 8]);
  float v[8];
#pragma unroll
  for (int j = 0; j < 8; ++j) v[j] = bf2f((u16)in8[j]);
  float mx = v[0];
#pragma unroll
  for (int j = 1; j < 8; ++j) mx = fmaxf(mx, v[j]);
#pragma unroll
  for (int o = 32; o; o >>= 1) mx = fmaxf(mx, __shfl_xor(mx, o, 64));
  __shared__ float redm[4], reds[4];
  if (lane == 0) redm[wave] = mx;
  __syncthreads();
  mx = fmaxf(fmaxf(redm[0], redm[1]), fmaxf(redm[2], redm[3]));
  float sm = 0.f;
#pragma unroll
  for (int j = 0; j < 8; ++j) { v[j] = __expf(v[j] - mx); sm += v[j]; }
#pragma unroll
  for (int o = 32; o; o >>= 1) sm += __shfl_xor(sm, o, 64);
  if (lane == 0) reds[wave] = sm;
  __syncthreads();
  float inv = 1.0f / (reds[0] + reds[1] + reds[2] + reds[3]);
  short8 o8;
#pragma unroll
  for (int j = 0; j < 8; ++j) o8[j] = (short)f2bf(v[j] * inv);
  *reinterpret_cast<short8*>(&S[base + t * 8]) = o8;
}

extern "C" void kernel_launch(void* const* d_in, const int* in_sizes, int n_in,
                              void* d_out, int out_size, void* d_ws, size_t ws_size,
                              hipStream_t stream) {
  const float* x  = (const float*)d_in[0];
  const float* wq = (const float*)d_in[1];
  const float* wk = (const float*)d_in[2];
  const float* wv = (const float*)d_in[3];
  float* out = (float*)d_out;
  char* ws = (char*)d_ws;

  // workspace layout (bytes); vt overlays xb (dead after projection GEMM)
  u16*  xb   = (u16*)(ws);                          //  33,554,432  x bf16 [16384][1024]
  u16*  vt   = (u16*)(ws);                          //  33,554,432  [8][1024][2048] (after xb dead)
  u16*  wcat = (u16*)(ws + 33554432);               //   6,291,456  [wq;wk;wv] bf16 [3072][1024]
  float* cosT = (float*)(ws + 39845888);            //   4,194,304  [2048][512]
  float* sinT = (float*)(ws + 44040192);            //   4,194,304
  u16*  qkv  = (u16*)(ws + 48234496);               // 100,663,296  [16384][3072] bf16 (Q|K|V)
  u16*  S    = (u16*)(ws + 148897792);              //  67,108,864  [8][2048][2048] bf16 (P in place)
  const size_t NEED = 216006656;                    // 216.0 MB total
  if (ws_size < NEED) return;  // diagnostic guard

  cast_f32_bf16<<<2048, 256, 0, stream>>>(x, xb, 16384 * 1024);
  cast_f32_bf16<<<256, 256, 0, stream>>>(wq, wcat, 1024 * 1024);
  cast_f32_bf16<<<256, 256, 0, stream>>>(wk, wcat + 1024 * 1024, 1024 * 1024);
  cast_f32_bf16<<<256, 256, 0, stream>>>(wv, wcat + 2 * 1024 * 1024, 1024 * 1024);
  rope_tables<<<(2048 * 512) / 256, 256, 0, stream>>>(cosT, sinT);

  // QKV projection + fused RoPE on Q,K cols (<2048): [16384][1024]@[3072][1024]^T
  gemm_bt<u16><<<dim3(24, 128, 1), 256, 0, stream>>>(
      xb, wcat, qkv, 1024, 1024, 1024, 3072, 0, 0, 0, 1.0f,
      cosT, sinT, 2048);

  transpose_v<<<dim3(32, 64, 8), 256, 0, stream>>>(qkv, vt);   // xb region now dead

  // scores: per batch Qr[2048][1024] @ Kr^T -> S bf16, scale 1/sqrt(1024)
  gemm_bt<u16><<<dim3(16, 16, 8), 256, 0, stream>>>(
      qkv, qkv + 1024, S, 1024, 3072, 3072, 2048,
      2048L * 3072, 2048L * 3072, 2048L * 2048, 0.03125f,
      nullptr, nullptr, 0);

  softmax_rows_bf16<<<16384, 256, 0, stream>>>(S);

  // out: per batch P[2048][2048] bf16 @ Vt^T[1024][2048] -> fp32
  gemm_bt<float><<<dim3(8, 16, 8), 256, 0, stream>>>(
      S, vt, out, 2048, 2048, 2048, 1024,
      2048L * 2048, 1024L * 2048, 2048L * 1024, 1.0f,
      nullptr, nullptr, 0);
}

// Round 7
// 573.101 us; speedup vs baseline: 1.0358x; 1.0358x over previous
//
#include <hip/hip_runtime.h>
#include <hip/hip_bf16.h>
#include <cstdint>
#include <type_traits>

typedef unsigned short u16;
typedef __attribute__((ext_vector_type(8))) short short8;
typedef __attribute__((ext_vector_type(4))) float floatx4;

__device__ __forceinline__ u16 f2bf(float f) {
  union { float f; uint32_t u; } v; v.f = f;
  uint32_t u = v.u;
  return (u16)((u + 0x7FFFu + ((u >> 16) & 1u)) >> 16);
}
__device__ __forceinline__ float bf2f(u16 h) {
  union { uint32_t u; float f; } v; v.u = ((uint32_t)h) << 16;
  return v.f;
}

// global -> LDS direct, 16B per lane. LDS dest is wave-uniform base + lane*16
// (m104); global src is per-lane.
typedef const __attribute__((address_space(1))) char GChar;
typedef __attribute__((address_space(3))) char LChar;
__device__ __forceinline__ void gload_lds16(const void* g, void* l) {
  __builtin_amdgcn_global_load_lds((GChar*)g, (LChar*)l, 16, 0, 0);
}

// ---------------- elementwise: fp32 -> bf16 cast ----------------
__global__ void cast_f32_bf16(const float* __restrict__ src, u16* __restrict__ dst, int n) {
  int i = (blockIdx.x * blockDim.x + threadIdx.x) * 4;
  int stride = gridDim.x * blockDim.x * 4;
  for (; i < n; i += stride) {
    float4 v = *reinterpret_cast<const float4*>(src + i);
    ushort4 o;
    o.x = f2bf(v.x); o.y = f2bf(v.y); o.z = f2bf(v.z); o.w = f2bf(v.w);
    *reinterpret_cast<ushort4*>(dst + i) = o;
  }
}

// ---------------- RoPE tables (matches reference: theta=10000^(-2(i-1)/D)) --
__global__ void rope_tables(float* __restrict__ cosT, float* __restrict__ sinT) {
  int idx = blockIdx.x * blockDim.x + threadIdx.x;   // m*512 + i
  int m = idx >> 9;
  int i = idx & 511;
  double ex = -2.0 * ((double)i - 1.0) / 1024.0;
  double theta = exp(ex * log(10000.0));
  double ang = (double)m * theta;
  cosT[idx] = (float)cos(ang);
  sinT[idx] = (float)sin(ang);
}

// ---------------- GEMM-BT: C[i][j] = scale * sum_k A[i][k]*W[j][k] ---------
// A,W bf16 row-major; C fp32 or bf16. 128x128 tile, BK=32, 4 waves (2x2 of 64x64),
// mfma_f32_16x16x32_bf16, global_load_lds width-16 staging (m97 structure).
// NO XCD swizzle: for this grid the hw round-robin keeps per-XCD working sets
// (A ~2MB, W ~0.8MB) L2-resident; both hand swizzles measured 2.5-3x FETCH.
// ropeCols > 0: fused RoPE rotation on output cols < ropeCols (pairs via shfl).
template <typename CT>
__global__ __launch_bounds__(256) void gemm_bt(
    const u16* __restrict__ A, const u16* __restrict__ Bw, CT* __restrict__ C,
    int K, long lda, long ldb, long ldc,
    long strideA, long strideB, long strideC, float scale,
    const float* __restrict__ cosT, const float* __restrict__ sinT, int ropeCols)
{
  __shared__ u16 As[128 * 32];
  __shared__ u16 Bs[128 * 32];

  const int bz = blockIdx.z;
  A  += (long)bz * strideA;
  Bw += (long)bz * strideB;
  C  += (long)bz * strideC;

  const int tm = blockIdx.y, tn = blockIdx.x;
  const int t = threadIdx.x;
  const int lane = t & 63, wave = t >> 6;
  const int wm = (wave >> 1) * 64, wn = (wave & 1) * 64;

  // staging: thread t covers LDS elements t*8..t*8+7 => row t/4, col (t%4)*8
  const int srow = t >> 2;
  const int scol = (t & 3) * 8;
  const u16* Ag = A + (long)(tm * 128 + srow) * lda + scol;
  const u16* Bg = Bw + (long)(tn * 128 + srow) * ldb + scol;
  u16* AsW = As + wave * 512;   // wave-uniform LDS base (lane lands at +lane*8)
  u16* BsW = Bs + wave * 512;

  floatx4 acc[4][4];
#pragma unroll
  for (int m = 0; m < 4; ++m)
#pragma unroll
    for (int n = 0; n < 4; ++n) acc[m][n] = (floatx4){0.f, 0.f, 0.f, 0.f};

  const int arow = (lane & 15) * 32 + ((lane >> 4) * 8);  // frag offset: row*32+k
  const int nk = K >> 5;
  for (int kt = 0; kt < nk; ++kt) {
    __syncthreads();  // previous tile fully consumed
    const u16* ag = Ag + kt * 32;
    const u16* bg = Bg + kt * 32;
    gload_lds16(ag,             AsW);
    gload_lds16(ag + 64 * lda,  AsW + 2048);
    gload_lds16(bg,             BsW);
    gload_lds16(bg + 64 * ldb,  BsW + 2048);
    __syncthreads();  // drains vmcnt -> tile ready

    short8 af[4], bf[4];
#pragma unroll
    for (int m = 0; m < 4; ++m)
      af[m] = *reinterpret_cast<const short8*>(&As[(wm + m * 16) * 32 + arow]);
#pragma unroll
    for (int n = 0; n < 4; ++n)
      bf[n] = *reinterpret_cast<const short8*>(&Bs[(wn + n * 16) * 32 + arow]);
#pragma unroll
    for (int m = 0; m < 4; ++m)
#pragma unroll
      for (int n = 0; n < 4; ++n)
        acc[m][n] = __builtin_amdgcn_mfma_f32_16x16x32_bf16(af[m], bf[n], acc[m][n], 0, 0, 0);
  }

  // epilogue: C/D layout col=lane&15, row=(lane>>4)*4+r (m89/m91 verified)
  const long crow = (long)tm * 128 + wm + ((lane >> 4) << 2);
  const long ccol = (long)tn * 128 + wn + (lane & 15);
  const bool doRope = (ropeCols > 0) && (tn * 128 < ropeCols);  // block-uniform
  const int par = lane & 1;
#pragma unroll
  for (int m = 0; m < 4; ++m)
#pragma unroll
    for (int n = 0; n < 4; ++n)
#pragma unroll
      for (int r = 0; r < 4; ++r) {
        long row = crow + m * 16 + r;
        long col = ccol + n * 16;
        float val = acc[m][n][r] * scale;
        if (doRope) {
          // pair (even col = te, odd col = to) lives on lanes (l, l^1)
          float other = __shfl_xor(val, 1, 64);
          int i  = ((int)(col & 1023)) >> 1;   // Q (col<1024) and K (col-1024)
          int mm = (int)(row & 2047);
          float c = cosT[mm * 512 + i];
          float s = sinT[mm * 512 + i];
          // even lane: re = te*c + to*s ; odd lane: ro = -te*s + to*c
          val = par ? (val * c - other * s) : (val * c + other * s);
        }
        if constexpr (std::is_same<CT, u16>::value)
          C[row * ldc + col] = f2bf(val);
        else
          C[row * ldc + col] = val;
      }
}

// ---------------- V transpose: vt[b][d][m] = V[b][m][d] ---------------------
__global__ void transpose_v(const u16* __restrict__ qkv, u16* __restrict__ vt) {
  __shared__ u16 tile[32][33];
  int b = blockIdx.z;
  int m0 = blockIdx.y * 32, d0 = blockIdx.x * 32;
  int tx = threadIdx.x & 31, ty = threadIdx.x >> 5;  // 32x8
#pragma unroll
  for (int r = ty; r < 32; r += 8)
    tile[r][tx] = qkv[(long)(b * 2048 + m0 + r) * 3072 + 2048 + d0 + tx];
  __syncthreads();
#pragma unroll
  for (int r = ty; r < 32; r += 8)
    vt[(long)b * 1024 * 2048 + (long)(d0 + r) * 2048 + m0 + tx] = tile[tx][r];
}

// ------------- row softmax on bf16 scores, P bf16 written in place ----------
__global__ __launch_bounds__(256) void softmax_rows_bf16(u16* __restrict__ S) {
  const long base = (long)blockIdx.x * 2048;
  const int t = threadIdx.x, lane = t & 63, wave = t >> 6;
  short8 in8 = *reinterpret_cast<const short8*>(&S[base + t * 8]);
  float v[8];
#pragma unroll
  for (int j = 0; j < 8; ++j) v[j] = bf2f((u16)in8[j]);
  float mx = v[0];
#pragma unroll
  for (int j = 1; j < 8; ++j) mx = fmaxf(mx, v[j]);
#pragma unroll
  for (int o = 32; o; o >>= 1) mx = fmaxf(mx, __shfl_xor(mx, o, 64));
  __shared__ float redm[4], reds[4];
  if (lane == 0) redm[wave] = mx;
  __syncthreads();
  mx = fmaxf(fmaxf(redm[0], redm[1]), fmaxf(redm[2], redm[3]));
  float sm = 0.f;
#pragma unroll
  for (int j = 0; j < 8; ++j) { v[j] = __expf(v[j] - mx); sm += v[j]; }
#pragma unroll
  for (int o = 32; o; o >>= 1) sm += __shfl_xor(sm, o, 64);
  if (lane == 0) reds[wave] = sm;
  __syncthreads();
  float inv = 1.0f / (reds[0] + reds[1] + reds[2] + reds[3]);
  short8 o8;
#pragma unroll
  for (int j = 0; j < 8; ++j) o8[j] = (short)f2bf(v[j] * inv);
  *reinterpret_cast<short8*>(&S[base + t * 8]) = o8;
}

extern "C" void kernel_launch(void* const* d_in, const int* in_sizes, int n_in,
                              void* d_out, int out_size, void* d_ws, size_t ws_size,
                              hipStream_t stream) {
  const float* x  = (const float*)d_in[0];
  const float* wq = (const float*)d_in[1];
  const float* wk = (const float*)d_in[2];
  const float* wv = (const float*)d_in[3];
  float* out = (float*)d_out;
  char* ws = (char*)d_ws;

  // workspace layout (bytes); vt overlays xb (dead after projection GEMM)
  u16*  xb   = (u16*)(ws);                          //  33,554,432  x bf16 [16384][1024]
  u16*  vt   = (u16*)(ws);                          //  33,554,432  [8][1024][2048] (after xb dead)
  u16*  wcat = (u16*)(ws + 33554432);               //   6,291,456  [wq;wk;wv] bf16 [3072][1024]
  float* cosT = (float*)(ws + 39845888);            //   4,194,304  [2048][512]
  float* sinT = (float*)(ws + 44040192);            //   4,194,304
  u16*  qkv  = (u16*)(ws + 48234496);               // 100,663,296  [16384][3072] bf16 (Q|K|V)
  u16*  S    = (u16*)(ws + 148897792);              //  67,108,864  [8][2048][2048] bf16 (P in place)
  const size_t NEED = 216006656;                    // 216.0 MB total
  if (ws_size < NEED) return;  // diagnostic guard

  cast_f32_bf16<<<2048, 256, 0, stream>>>(x, xb, 16384 * 1024);
  cast_f32_bf16<<<256, 256, 0, stream>>>(wq, wcat, 1024 * 1024);
  cast_f32_bf16<<<256, 256, 0, stream>>>(wk, wcat + 1024 * 1024, 1024 * 1024);
  cast_f32_bf16<<<256, 256, 0, stream>>>(wv, wcat + 2 * 1024 * 1024, 1024 * 1024);
  rope_tables<<<(2048 * 512) / 256, 256, 0, stream>>>(cosT, sinT);

  // QKV projection + fused RoPE on Q,K cols (<2048): [16384][1024]@[3072][1024]^T
  gemm_bt<u16><<<dim3(24, 128, 1), 256, 0, stream>>>(
      xb, wcat, qkv, 1024, 1024, 1024, 3072, 0, 0, 0, 1.0f,
      cosT, sinT, 2048);

  transpose_v<<<dim3(32, 64, 8), 256, 0, stream>>>(qkv, vt);   // xb region now dead

  // scores: per batch Qr[2048][1024] @ Kr^T -> S bf16, scale 1/sqrt(1024)
  gemm_bt<u16><<<dim3(16, 16, 8), 256, 0, stream>>>(
      qkv, qkv + 1024, S, 1024, 3072, 3072, 2048,
      2048L * 3072, 2048L * 3072, 2048L * 2048, 0.03125f,
      nullptr, nullptr, 0);

  softmax_rows_bf16<<<16384, 256, 0, stream>>>(S);

  // out: per batch P[2048][2048] bf16 @ Vt^T[1024][2048] -> fp32
  gemm_bt<float><<<dim3(8, 16, 8), 256, 0, stream>>>(
      S, vt, out, 2048, 2048, 2048, 1024,
      2048L * 2048, 1024L * 2048, 2048L * 1024, 1.0f,
      nullptr, nullptr, 0);
}

// Round 8
// 468.883 us; speedup vs baseline: 1.2661x; 1.2223x over previous
//
#include <hip/hip_runtime.h>
#include <hip/hip_bf16.h>
#include <cstdint>
#include <type_traits>

typedef unsigned short u16;
typedef __attribute__((ext_vector_type(8))) short short8;
typedef __attribute__((ext_vector_type(4))) float floatx4;

__device__ __forceinline__ u16 f2bf(float f) {
  union { float f; uint32_t u; } v; v.f = f;
  uint32_t u = v.u;
  return (u16)((u + 0x7FFFu + ((u >> 16) & 1u)) >> 16);
}
__device__ __forceinline__ float bf2f(u16 h) {
  union { uint32_t u; float f; } v; v.u = ((uint32_t)h) << 16;
  return v.f;
}

typedef const __attribute__((address_space(1))) char GChar;
typedef __attribute__((address_space(3))) char LChar;
__device__ __forceinline__ void gload_lds16(const void* g, void* l) {
  __builtin_amdgcn_global_load_lds((GChar*)g, (LChar*)l, 16, 0, 0);
}

// ---------------- elementwise: fp32 -> bf16 cast ----------------
__global__ void cast_f32_bf16(const float* __restrict__ src, u16* __restrict__ dst, int n) {
  int i = (blockIdx.x * blockDim.x + threadIdx.x) * 4;
  int stride = gridDim.x * blockDim.x * 4;
  for (; i < n; i += stride) {
    float4 v = *reinterpret_cast<const float4*>(src + i);
    ushort4 o;
    o.x = f2bf(v.x); o.y = f2bf(v.y); o.z = f2bf(v.z); o.w = f2bf(v.w);
    *reinterpret_cast<ushort4*>(dst + i) = o;
  }
}

// ---------------- RoPE tables (matches reference: theta=10000^(-2(i-1)/D)) --
__global__ void rope_tables(float* __restrict__ cosT, float* __restrict__ sinT) {
  int idx = blockIdx.x * blockDim.x + threadIdx.x;   // m*512 + i
  int m = idx >> 9;
  int i = idx & 511;
  double ex = -2.0 * ((double)i - 1.0) / 1024.0;
  double theta = exp(ex * log(10000.0));
  double ang = (double)m * theta;
  cosT[idx] = (float)cos(ang);
  sinT[idx] = (float)sin(ang);
}

// ---------------- RoPE in-place on Q,K halves of qkv cat (round-4 proven) ---
__global__ void rope_apply(u16* __restrict__ qkv,
                           const float* __restrict__ cosT, const float* __restrict__ sinT) {
  int g = blockIdx.x * blockDim.x + threadIdx.x;   // 16384 rows * 128 groups
  int row = g >> 7;
  int grp = g & 127;
  int m = row & 2047;
  int p0 = grp * 4;
  float4 c = *reinterpret_cast<const float4*>(&cosT[m * 512 + p0]);
  float4 s = *reinterpret_cast<const float4*>(&sinT[m * 512 + p0]);
  float cc[4] = {c.x, c.y, c.z, c.w};
  float ss[4] = {s.x, s.y, s.z, s.w};
  long base = (long)row * 3072 + p0 * 2;
#pragma unroll
  for (int h = 0; h < 2; ++h) {
    u16* p = qkv + base + h * 1024;
    short8 v = *reinterpret_cast<const short8*>(p);
    short8 o;
#pragma unroll
    for (int j = 0; j < 4; ++j) {
      float te = bf2f((u16)v[2 * j]);
      float to = bf2f((u16)v[2 * j + 1]);
      o[2 * j]     = (short)f2bf(te * cc[j] + to * ss[j]);
      o[2 * j + 1] = (short)f2bf(-te * ss[j] + to * cc[j]);
    }
    *reinterpret_cast<short8*>(p) = o;
  }
}

// ---------------- 256x256 8-wave pipelined GEMM-BT -------------------------
// C[i][j] = scale * sum_k A[i][k]*W[j][k]; A,W bf16 row-major.
// BM=BN=256, BK=64, 512 thr (8 waves 2Mx4N, 128x64 per wave), LDS 128KB dbuf.
// Per K-tile: 4 phases {stage half-tile of kt+1 | ds_read frags | barrier |
// setprio(1) 16 MFMA setprio(0) | barrier}; ONE counted vmcnt(2) per tile
// (never 0 until the last tile). LDS XOR-swizzle c^=((r>>2)&3)<<4 applied
// rule-21 style: linear gload_lds dest + inverse-swizzled GLOBAL src +
// swizzled ds_read (16-way -> 4-way bank conflict).
template <typename CT>
__global__ __launch_bounds__(512, 2) void gemm256(
    const u16* __restrict__ A, const u16* __restrict__ Bw, CT* __restrict__ C,
    int K, long lda, long ldb, long ldc,
    long strideA, long strideB, long strideC, float scale)
{
  __shared__ u16 lds[65536];   // A0 | A1 | B0 | B1, 16384 u16 (32KB) each

  const int bz = blockIdx.z;
  A  += (long)bz * strideA;
  Bw += (long)bz * strideB;
  C  += (long)bz * strideC;

  const int tm = blockIdx.y, tn = blockIdx.x;
  const int t = threadIdx.x;
  const int lane = t & 63, wave = t >> 6;
  const int wm = wave >> 2, wn = wave & 3;      // 2 x 4 waves

  const long arow0 = (long)tm * 256;
  const long brow0 = (long)tn * 256;

  // staging geometry: per gload instr, thread t covers (row sr, 16B at scs)
  const int sr  = t >> 3;                        // 0..63 within 64-row slab
  const int scs = ((t & 7) * 8) ^ (((sr >> 2) & 3) << 4);  // inverse-swizzled src col

  u16* const Ab0 = lds;
  u16* const Ab1 = lds + 16384;
  u16* const Bb0 = lds + 32768;
  u16* const Bb1 = lds + 49152;

  // read-side swizzle constants
  const int Xr = (((lane & 15) >> 2) & 3) << 4;
  const int kc = (lane >> 4) * 8;                // k-offset within 32-slice

  floatx4 acc[8][4];
#pragma unroll
  for (int m = 0; m < 8; ++m)
#pragma unroll
    for (int n = 0; n < 4; ++n) acc[m][n] = (floatx4){0.f, 0.f, 0.f, 0.f};

  const int nkt = K >> 6;

  // prologue: stage tile 0 (B halves then A halves; 8 loads)
#pragma unroll
  for (int h = 0; h < 2; ++h) {
    const u16* g = Bw + (brow0 + h * 128 + sr) * ldb + scs;
    u16* d = Bb0 + h * 8192 + t * 8;
    gload_lds16(g, d);
    gload_lds16(g + 64 * ldb, d + 4096);
  }
#pragma unroll
  for (int h = 0; h < 2; ++h) {
    const u16* g = A + (arow0 + h * 128 + sr) * lda + scs;
    u16* d = Ab0 + h * 8192 + t * 8;
    gload_lds16(g, d);
    gload_lds16(g + 64 * lda, d + 4096);
  }

  for (int kt = 0; kt < nkt; ++kt) {
    u16* const Ac = (kt & 1) ? Ab1 : Ab0;
    u16* const Bc = (kt & 1) ? Bb1 : Bb0;
    u16* const An = (kt & 1) ? Ab0 : Ab1;
    u16* const Bn = (kt & 1) ? Bb0 : Bb1;
    const bool pf = (kt + 1 < nkt);
    const int kn = (kt + 1) * 64;

    short8 bfr[4][2];

#pragma unroll
    for (int q = 0; q < 4; ++q) {
      // stage one half-tile of kt+1: q0=Bh0 q1=Bh1 q2=Ah0 q3=Ah1
      if (pf) {
        if (q < 2) {
          const u16* g = Bw + (brow0 + q * 128 + sr) * ldb + kn + scs;
          u16* d = Bn + q * 8192 + t * 8;
          gload_lds16(g, d);
          gload_lds16(g + 64 * ldb, d + 4096);
        } else {
          const int h = q - 2;
          const u16* g = A + (arow0 + h * 128 + sr) * lda + kn + scs;
          u16* d = An + h * 8192 + t * 8;
          gload_lds16(g, d);
          gload_lds16(g + 64 * lda, d + 4096);
        }
      }
      if (q == 0) {
        // tile kt guaranteed landed after this wait+barrier; allows the 2
        // loads just issued for kt+1 to stay in flight (never drain to 0).
        if (pf) asm volatile("s_waitcnt vmcnt(2)" ::: "memory");
        else    asm volatile("s_waitcnt vmcnt(0)" ::: "memory");
        __builtin_amdgcn_s_barrier();
        // B-frags for the whole tile (reused across all 4 M-quadrants)
#pragma unroll
        for (int n = 0; n < 4; ++n)
#pragma unroll
          for (int kk = 0; kk < 2; ++kk)
            bfr[n][kk] = *reinterpret_cast<const short8*>(
                &Bc[(wn * 64 + n * 16 + (lane & 15)) * 64 + ((kk * 32 + kc) ^ Xr)]);
      }
      // A-frags for this quadrant (m = 2q, 2q+1)
      short8 afr[2][2];
#pragma unroll
      for (int i = 0; i < 2; ++i)
#pragma unroll
        for (int kk = 0; kk < 2; ++kk)
          afr[i][kk] = *reinterpret_cast<const short8*>(
              &Ac[(wm * 128 + (2 * q + i) * 16 + (lane & 15)) * 64 + ((kk * 32 + kc) ^ Xr)]);

      __builtin_amdgcn_s_barrier();
      __builtin_amdgcn_s_setprio(1);
#pragma unroll
      for (int i = 0; i < 2; ++i)
#pragma unroll
        for (int kk = 0; kk < 2; ++kk)
#pragma unroll
          for (int n = 0; n < 4; ++n)
            acc[2 * q + i][n] = __builtin_amdgcn_mfma_f32_16x16x32_bf16(
                afr[i][kk], bfr[n][kk], acc[2 * q + i][n], 0, 0, 0);
      __builtin_amdgcn_s_setprio(0);
      __builtin_amdgcn_s_barrier();
    }
  }

  // epilogue: C/D layout col=lane&15, row=(lane>>4)*4+r (m89/m91 verified)
  const long crow = arow0 + wm * 128 + ((lane >> 4) << 2);
  const long ccol = brow0 + wn * 64 + (lane & 15);
#pragma unroll
  for (int m = 0; m < 8; ++m)
#pragma unroll
    for (int n = 0; n < 4; ++n)
#pragma unroll
      for (int r = 0; r < 4; ++r) {
        float val = acc[m][n][r] * scale;
        long row = crow + m * 16 + r;
        long col = ccol + n * 16;
        if constexpr (std::is_same<CT, u16>::value)
          C[row * ldc + col] = f2bf(val);
        else
          C[row * ldc + col] = val;
      }
}

// ---------------- V transpose: vt[b][d][m] = V[b][m][d] ---------------------
__global__ void transpose_v(const u16* __restrict__ qkv, u16* __restrict__ vt) {
  __shared__ u16 tile[32][33];
  int b = blockIdx.z;
  int m0 = blockIdx.y * 32, d0 = blockIdx.x * 32;
  int tx = threadIdx.x & 31, ty = threadIdx.x >> 5;  // 32x8
#pragma unroll
  for (int r = ty; r < 32; r += 8)
    tile[r][tx] = qkv[(long)(b * 2048 + m0 + r) * 3072 + 2048 + d0 + tx];
  __syncthreads();
#pragma unroll
  for (int r = ty; r < 32; r += 8)
    vt[(long)b * 1024 * 2048 + (long)(d0 + r) * 2048 + m0 + tx] = tile[tx][r];
}

// ------------- row softmax on bf16 scores, P bf16 written in place ----------
__global__ __launch_bounds__(256) void softmax_rows_bf16(u16* __restrict__ S) {
  const long base = (long)blockIdx.x * 2048;
  const int t = threadIdx.x, lane = t & 63, wave = t >> 6;
  short8 in8 = *reinterpret_cast<const short8*>(&S[base + t * 8]);
  float v[8];
#pragma unroll
  for (int j = 0; j < 8; ++j) v[j] = bf2f((u16)in8[j]);
  float mx = v[0];
#pragma unroll
  for (int j = 1; j < 8; ++j) mx = fmaxf(mx, v[j]);
#pragma unroll
  for (int o = 32; o; o >>= 1) mx = fmaxf(mx, __shfl_xor(mx, o, 64));
  __shared__ float redm[4], reds[4];
  if (lane == 0) redm[wave] = mx;
  __syncthreads();
  mx = fmaxf(fmaxf(redm[0], redm[1]), fmaxf(redm[2], redm[3]));
  float sm = 0.f;
#pragma unroll
  for (int j = 0; j < 8; ++j) { v[j] = __expf(v[j] - mx); sm += v[j]; }
#pragma unroll
  for (int o = 32; o; o >>= 1) sm += __shfl_xor(sm, o, 64);
  if (lane == 0) reds[wave] = sm;
  __syncthreads();
  float inv = 1.0f / (reds[0] + reds[1] + reds[2] + reds[3]);
  short8 o8;
#pragma unroll
  for (int j = 0; j < 8; ++j) o8[j] = (short)f2bf(v[j] * inv);
  *reinterpret_cast<short8*>(&S[base + t * 8]) = o8;
}

extern "C" void kernel_launch(void* const* d_in, const int* in_sizes, int n_in,
                              void* d_out, int out_size, void* d_ws, size_t ws_size,
                              hipStream_t stream) {
  const float* x  = (const float*)d_in[0];
  const float* wq = (const float*)d_in[1];
  const float* wk = (const float*)d_in[2];
  const float* wv = (const float*)d_in[3];
  float* out = (float*)d_out;
  char* ws = (char*)d_ws;

  // workspace layout (bytes); vt overlays xb (dead after projection GEMM)
  u16*  xb   = (u16*)(ws);                          //  33,554,432  x bf16 [16384][1024]
  u16*  vt   = (u16*)(ws);                          //  33,554,432  [8][1024][2048] (after xb dead)
  u16*  wcat = (u16*)(ws + 33554432);               //   6,291,456  [wq;wk;wv] bf16 [3072][1024]
  float* cosT = (float*)(ws + 39845888);            //   4,194,304  [2048][512]
  float* sinT = (float*)(ws + 44040192);            //   4,194,304
  u16*  qkv  = (u16*)(ws + 48234496);               // 100,663,296  [16384][3072] bf16 (Q|K|V)
  u16*  S    = (u16*)(ws + 148897792);              //  67,108,864  [8][2048][2048] bf16 (P in place)
  const size_t NEED = 216006656;                    // 216.0 MB total
  if (ws_size < NEED) return;  // diagnostic guard

  cast_f32_bf16<<<2048, 256, 0, stream>>>(x, xb, 16384 * 1024);
  cast_f32_bf16<<<256, 256, 0, stream>>>(wq, wcat, 1024 * 1024);
  cast_f32_bf16<<<256, 256, 0, stream>>>(wk, wcat + 1024 * 1024, 1024 * 1024);
  cast_f32_bf16<<<256, 256, 0, stream>>>(wv, wcat + 2 * 1024 * 1024, 1024 * 1024);
  rope_tables<<<(2048 * 512) / 256, 256, 0, stream>>>(cosT, sinT);

  // QKV projection: [16384][1024] @ [3072][1024]^T -> [16384][3072] bf16
  gemm256<u16><<<dim3(12, 64, 1), 512, 0, stream>>>(
      xb, wcat, qkv, 1024, 1024, 1024, 3072, 0, 0, 0, 1.0f);

  rope_apply<<<(16384 * 128) / 256, 256, 0, stream>>>(qkv, cosT, sinT);
  transpose_v<<<dim3(32, 64, 8), 256, 0, stream>>>(qkv, vt);   // xb region now dead

  // scores: per batch Qr[2048][1024] @ Kr^T -> S bf16, scale 1/sqrt(1024)
  gemm256<u16><<<dim3(8, 8, 8), 512, 0, stream>>>(
      qkv, qkv + 1024, S, 1024, 3072, 3072, 2048,
      2048L * 3072, 2048L * 3072, 2048L * 2048, 0.03125f);

  softmax_rows_bf16<<<16384, 256, 0, stream>>>(S);

  // out: per batch P[2048][2048] bf16 @ Vt^T[1024][2048] -> fp32
  gemm256<float><<<dim3(4, 8, 8), 512, 0, stream>>>(
      S, vt, out, 2048, 2048, 2048, 1024,
      2048L * 2048, 1024L * 2048, 2048L * 1024, 1.0f);
}

// Round 9
// 441.979 us; speedup vs baseline: 1.3431x; 1.0609x over previous
//
#include <hip/hip_runtime.h>
#include <hip/hip_bf16.h>
#include <cstdint>
#include <type_traits>

typedef unsigned short u16;
typedef __attribute__((ext_vector_type(8))) short short8;
typedef __attribute__((ext_vector_type(4))) float floatx4;

__device__ __forceinline__ u16 f2bf(float f) {
  union { float f; uint32_t u; } v; v.f = f;
  uint32_t u = v.u;
  return (u16)((u + 0x7FFFu + ((u >> 16) & 1u)) >> 16);
}
__device__ __forceinline__ float bf2f(u16 h) {
  union { uint32_t u; float f; } v; v.u = ((uint32_t)h) << 16;
  return v.f;
}

typedef const __attribute__((address_space(1))) char GChar;
typedef __attribute__((address_space(3))) char LChar;
__device__ __forceinline__ void gload_lds16(const void* g, void* l) {
  __builtin_amdgcn_global_load_lds((GChar*)g, (LChar*)l, 16, 0, 0);
}

// ---------------- elementwise: fp32 -> bf16 cast ----------------
__global__ void cast_f32_bf16(const float* __restrict__ src, u16* __restrict__ dst, int n) {
  int i = (blockIdx.x * blockDim.x + threadIdx.x) * 4;
  int stride = gridDim.x * blockDim.x * 4;
  for (; i < n; i += stride) {
    float4 v = *reinterpret_cast<const float4*>(src + i);
    ushort4 o;
    o.x = f2bf(v.x); o.y = f2bf(v.y); o.z = f2bf(v.z); o.w = f2bf(v.w);
    *reinterpret_cast<ushort4*>(dst + i) = o;
  }
}

// ---------------- RoPE tables (matches reference: theta=10000^(-2(i-1)/D)) --
__global__ void rope_tables(float* __restrict__ cosT, float* __restrict__ sinT) {
  int idx = blockIdx.x * blockDim.x + threadIdx.x;   // m*512 + i
  int m = idx >> 9;
  int i = idx & 511;
  double ex = -2.0 * ((double)i - 1.0) / 1024.0;
  double theta = exp(ex * log(10000.0));
  double ang = (double)m * theta;
  cosT[idx] = (float)cos(ang);
  sinT[idx] = (float)sin(ang);
}

// ---------------- RoPE in-place on Q,K halves of qkv cat --------------------
__global__ void rope_apply(u16* __restrict__ qkv,
                           const float* __restrict__ cosT, const float* __restrict__ sinT) {
  int g = blockIdx.x * blockDim.x + threadIdx.x;   // 16384 rows * 128 groups
  int row = g >> 7;
  int grp = g & 127;
  int m = row & 2047;
  int p0 = grp * 4;
  float4 c = *reinterpret_cast<const float4*>(&cosT[m * 512 + p0]);
  float4 s = *reinterpret_cast<const float4*>(&sinT[m * 512 + p0]);
  float cc[4] = {c.x, c.y, c.z, c.w};
  float ss[4] = {s.x, s.y, s.z, s.w};
  long base = (long)row * 3072 + p0 * 2;
#pragma unroll
  for (int h = 0; h < 2; ++h) {
    u16* p = qkv + base + h * 1024;
    short8 v = *reinterpret_cast<const short8*>(p);
    short8 o;
#pragma unroll
    for (int j = 0; j < 4; ++j) {
      float te = bf2f((u16)v[2 * j]);
      float to = bf2f((u16)v[2 * j + 1]);
      o[2 * j]     = (short)f2bf(te * cc[j] + to * ss[j]);
      o[2 * j + 1] = (short)f2bf(-te * ss[j] + to * cc[j]);
    }
    *reinterpret_cast<short8*>(p) = o;
  }
}

// ---------------- 256x256 8-wave pipelined GEMM-BT -------------------------
// C[i][j] = scale * sum_k A[i][k]*W[j][k]; A,W bf16 row-major.
// BM=BN=256, BK=64, 512 thr (8 waves 2Mx4N, 128x64 per wave), LDS 128KB dbuf.
// Per K-tile: 4 phases {stage half-tile of kt+1 | ds_read frags | barrier |
// setprio(1) 16 MFMA setprio(0) | barrier}; ONE counted vmcnt(2) per tile.
// LDS XOR-swizzle (16B granular, G4 formula): elem ^= (row&7)<<3 — 8 distinct
// 16B slots per 128B row -> rows r,r+8 alias 2-way (free, m136). Applied
// rule-21 both-sides: linear gload_lds dest + inverse-swizzled GLOBAL src +
// swizzled ds_read.
template <typename CT>
__global__ __launch_bounds__(512, 2) void gemm256(
    const u16* __restrict__ A, const u16* __restrict__ Bw, CT* __restrict__ C,
    int K, long lda, long ldb, long ldc,
    long strideA, long strideB, long strideC, float scale)
{
  __shared__ u16 lds[65536];   // A0 | A1 | B0 | B1, 16384 u16 (32KB) each

  const int bz = blockIdx.z;
  A  += (long)bz * strideA;
  Bw += (long)bz * strideB;
  C  += (long)bz * strideC;

  const int tm = blockIdx.y, tn = blockIdx.x;
  const int t = threadIdx.x;
  const int lane = t & 63, wave = t >> 6;
  const int wm = wave >> 2, wn = wave & 3;      // 2 x 4 waves

  const long arow0 = (long)tm * 256;
  const long brow0 = (long)tn * 256;

  // staging geometry: per gload instr, thread t covers (row sr, 16B slot t&7)
  const int sr  = t >> 3;                                  // 0..63 row in slab
  const int scs = ((t & 7) * 8) ^ ((sr & 7) << 3);         // inverse-swizzled src col

  u16* const Ab0 = lds;
  u16* const Ab1 = lds + 16384;
  u16* const Bb0 = lds + 32768;
  u16* const Bb1 = lds + 49152;

  // read-side swizzle: row&7 == lane&7 for all frag rows (offsets are mult of 8)
  const int Xr = (lane & 7) << 3;
  const int kc = (lane >> 4) * 8;                // k-offset within 32-slice

  floatx4 acc[8][4];
#pragma unroll
  for (int m = 0; m < 8; ++m)
#pragma unroll
    for (int n = 0; n < 4; ++n) acc[m][n] = (floatx4){0.f, 0.f, 0.f, 0.f};

  const int nkt = K >> 6;

  // prologue: stage tile 0 (B halves then A halves; 8 loads)
#pragma unroll
  for (int h = 0; h < 2; ++h) {
    const u16* g = Bw + (brow0 + h * 128 + sr) * ldb + scs;
    u16* d = Bb0 + h * 8192 + t * 8;
    gload_lds16(g, d);
    gload_lds16(g + 64 * ldb, d + 4096);
  }
#pragma unroll
  for (int h = 0; h < 2; ++h) {
    const u16* g = A + (arow0 + h * 128 + sr) * lda + scs;
    u16* d = Ab0 + h * 8192 + t * 8;
    gload_lds16(g, d);
    gload_lds16(g + 64 * lda, d + 4096);
  }

  for (int kt = 0; kt < nkt; ++kt) {
    u16* const Ac = (kt & 1) ? Ab1 : Ab0;
    u16* const Bc = (kt & 1) ? Bb1 : Bb0;
    u16* const An = (kt & 1) ? Ab0 : Ab1;
    u16* const Bn = (kt & 1) ? Bb0 : Bb1;
    const bool pf = (kt + 1 < nkt);
    const int kn = (kt + 1) * 64;

    short8 bfr[4][2];

#pragma unroll
    for (int q = 0; q < 4; ++q) {
      // stage one half-tile of kt+1: q0=Bh0 q1=Bh1 q2=Ah0 q3=Ah1
      if (pf) {
        if (q < 2) {
          const u16* g = Bw + (brow0 + q * 128 + sr) * ldb + kn + scs;
          u16* d = Bn + q * 8192 + t * 8;
          gload_lds16(g, d);
          gload_lds16(g + 64 * ldb, d + 4096);
        } else {
          const int h = q - 2;
          const u16* g = A + (arow0 + h * 128 + sr) * lda + kn + scs;
          u16* d = An + h * 8192 + t * 8;
          gload_lds16(g, d);
          gload_lds16(g + 64 * lda, d + 4096);
        }
      }
      if (q == 0) {
        // tile kt landed after this wait+barrier; the 2 loads just issued
        // for kt+1 stay in flight (never drain to 0 mid-loop).
        if (pf) asm volatile("s_waitcnt vmcnt(2)" ::: "memory");
        else    asm volatile("s_waitcnt vmcnt(0)" ::: "memory");
        __builtin_amdgcn_s_barrier();
        // B-frags for the whole tile (reused across all 4 M-quadrants)
#pragma unroll
        for (int n = 0; n < 4; ++n)
#pragma unroll
          for (int kk = 0; kk < 2; ++kk)
            bfr[n][kk] = *reinterpret_cast<const short8*>(
                &Bc[(wn * 64 + n * 16 + (lane & 15)) * 64 + ((kk * 32 + kc) ^ Xr)]);
      }
      // A-frags for this quadrant (m = 2q, 2q+1)
      short8 afr[2][2];
#pragma unroll
      for (int i = 0; i < 2; ++i)
#pragma unroll
        for (int kk = 0; kk < 2; ++kk)
          afr[i][kk] = *reinterpret_cast<const short8*>(
              &Ac[(wm * 128 + (2 * q + i) * 16 + (lane & 15)) * 64 + ((kk * 32 + kc) ^ Xr)]);

      __builtin_amdgcn_s_barrier();
      __builtin_amdgcn_s_setprio(1);
#pragma unroll
      for (int i = 0; i < 2; ++i)
#pragma unroll
        for (int kk = 0; kk < 2; ++kk)
#pragma unroll
          for (int n = 0; n < 4; ++n)
            acc[2 * q + i][n] = __builtin_amdgcn_mfma_f32_16x16x32_bf16(
                afr[i][kk], bfr[n][kk], acc[2 * q + i][n], 0, 0, 0);
      __builtin_amdgcn_s_setprio(0);
      __builtin_amdgcn_s_barrier();
    }
  }

  // epilogue: C/D layout col=lane&15, row=(lane>>4)*4+r (m89/m91 verified)
  const long crow = arow0 + wm * 128 + ((lane >> 4) << 2);
  const long ccol = brow0 + wn * 64 + (lane & 15);
#pragma unroll
  for (int m = 0; m < 8; ++m)
#pragma unroll
    for (int n = 0; n < 4; ++n)
#pragma unroll
      for (int r = 0; r < 4; ++r) {
        float val = acc[m][n][r] * scale;
        long row = crow + m * 16 + r;
        long col = ccol + n * 16;
        if constexpr (std::is_same<CT, u16>::value)
          C[row * ldc + col] = f2bf(val);
        else
          C[row * ldc + col] = val;
      }
}

// ---------------- V transpose: vt[b][d][m] = V[b][m][d] ---------------------
__global__ void transpose_v(const u16* __restrict__ qkv, u16* __restrict__ vt) {
  __shared__ u16 tile[32][33];
  int b = blockIdx.z;
  int m0 = blockIdx.y * 32, d0 = blockIdx.x * 32;
  int tx = threadIdx.x & 31, ty = threadIdx.x >> 5;  // 32x8
#pragma unroll
  for (int r = ty; r < 32; r += 8)
    tile[r][tx] = qkv[(long)(b * 2048 + m0 + r) * 3072 + 2048 + d0 + tx];
  __syncthreads();
#pragma unroll
  for (int r = ty; r < 32; r += 8)
    vt[(long)b * 1024 * 2048 + (long)(d0 + r) * 2048 + m0 + tx] = tile[tx][r];
}

// ------------- row softmax on bf16 scores, P bf16 written in place ----------
__global__ __launch_bounds__(256) void softmax_rows_bf16(u16* __restrict__ S) {
  const long base = (long)blockIdx.x * 2048;
  const int t = threadIdx.x, lane = t & 63, wave = t >> 6;
  short8 in8 = *reinterpret_cast<const short8*>(&S[base + t * 8]);
  float v[8];
#pragma unroll
  for (int j = 0; j < 8; ++j) v[j] = bf2f((u16)in8[j]);
  float mx = v[0];
#pragma unroll
  for (int j = 1; j < 8; ++j) mx = fmaxf(mx, v[j]);
#pragma unroll
  for (int o = 32; o; o >>= 1) mx = fmaxf(mx, __shfl_xor(mx, o, 64));
  __shared__ float redm[4], reds[4];
  if (lane == 0) redm[wave] = mx;
  __syncthreads();
  mx = fmaxf(fmaxf(redm[0], redm[1]), fmaxf(redm[2], redm[3]));
  float sm = 0.f;
#pragma unroll
  for (int j = 0; j < 8; ++j) { v[j] = __expf(v[j] - mx); sm += v[j]; }
#pragma unroll
  for (int o = 32; o; o >>= 1) sm += __shfl_xor(sm, o, 64);
  if (lane == 0) reds[wave] = sm;
  __syncthreads();
  float inv = 1.0f / (reds[0] + reds[1] + reds[2] + reds[3]);
  short8 o8;
#pragma unroll
  for (int j = 0; j < 8; ++j) o8[j] = (short)f2bf(v[j] * inv);
  *reinterpret_cast<short8*>(&S[base + t * 8]) = o8;
}

extern "C" void kernel_launch(void* const* d_in, const int* in_sizes, int n_in,
                              void* d_out, int out_size, void* d_ws, size_t ws_size,
                              hipStream_t stream) {
  const float* x  = (const float*)d_in[0];
  const float* wq = (const float*)d_in[1];
  const float* wk = (const float*)d_in[2];
  const float* wv = (const float*)d_in[3];
  float* out = (float*)d_out;
  char* ws = (char*)d_ws;

  // workspace layout (bytes); vt overlays xb (dead after projection GEMM)
  u16*  xb   = (u16*)(ws);                          //  33,554,432  x bf16 [16384][1024]
  u16*  vt   = (u16*)(ws);                          //  33,554,432  [8][1024][2048] (after xb dead)
  u16*  wcat = (u16*)(ws + 33554432);               //   6,291,456  [wq;wk;wv] bf16 [3072][1024]
  float* cosT = (float*)(ws + 39845888);            //   4,194,304  [2048][512]
  float* sinT = (float*)(ws + 44040192);            //   4,194,304
  u16*  qkv  = (u16*)(ws + 48234496);               // 100,663,296  [16384][3072] bf16 (Q|K|V)
  u16*  S    = (u16*)(ws + 148897792);              //  67,108,864  [8][2048][2048] bf16 (P in place)
  const size_t NEED = 216006656;                    // 216.0 MB total
  if (ws_size < NEED) return;  // diagnostic guard

  cast_f32_bf16<<<2048, 256, 0, stream>>>(x, xb, 16384 * 1024);
  cast_f32_bf16<<<256, 256, 0, stream>>>(wq, wcat, 1024 * 1024);
  cast_f32_bf16<<<256, 256, 0, stream>>>(wk, wcat + 1024 * 1024, 1024 * 1024);
  cast_f32_bf16<<<256, 256, 0, stream>>>(wv, wcat + 2 * 1024 * 1024, 1024 * 1024);
  rope_tables<<<(2048 * 512) / 256, 256, 0, stream>>>(cosT, sinT);

  // QKV projection: [16384][1024] @ [3072][1024]^T -> [16384][3072] bf16
  gemm256<u16><<<dim3(12, 64, 1), 512, 0, stream>>>(
      xb, wcat, qkv, 1024, 1024, 1024, 3072, 0, 0, 0, 1.0f);

  rope_apply<<<(16384 * 128) / 256, 256, 0, stream>>>(qkv, cosT, sinT);
  transpose_v<<<dim3(32, 64, 8), 256, 0, stream>>>(qkv, vt);   // xb region now dead

  // scores: per batch Qr[2048][1024] @ Kr^T -> S bf16, scale 1/sqrt(1024)
  gemm256<u16><<<dim3(8, 8, 8), 512, 0, stream>>>(
      qkv, qkv + 1024, S, 1024, 3072, 3072, 2048,
      2048L * 3072, 2048L * 3072, 2048L * 2048, 0.03125f);

  softmax_rows_bf16<<<16384, 256, 0, stream>>>(S);

  // out: per batch P[2048][2048] bf16 @ Vt^T[1024][2048] -> fp32
  gemm256<float><<<dim3(4, 8, 8), 512, 0, stream>>>(
      S, vt, out, 2048, 2048, 2048, 1024,
      2048L * 2048, 1024L * 2048, 2048L * 1024, 1.0f);
}